// Round 3
// baseline (1651.675 us; speedup 1.0000x reference)
//
#include <hip/hip_runtime.h>
#include <cstddef>
#include <cstdint>

// ---------------------------------------------------------------------------
// HGTConv, algebraically reduced:
//   softmax(scores).mean(-1) == 1/8 exactly  =>  attention path is dead code.
//   out = relu( mx @ (Wv@Wm@Wout)/8 + beta*((bv@Wm+bm)@Wout)/8 + bout + x )
//   with mx = segsum(x[src])/max(cnt,1), beta = (cnt>0),
//   and aggregation commuted past the linear map: agg(x)@Wf = agg((x@Wf)).
//
// R5: the ~290us residual outside the top dispatch was CONSTANT across three
// structures (17, 7, 7 nodes) -> per-node serialization, not kernel work.
// Collapse EVERYTHING into ONE persistent kernel (1024 blocks = 4/CU x 256CU,
// co-residency forced by __launch_bounds__(256,4)) with a device-scope
// generation barrier. 6 phases:
//   P0 GEMM1(T=Wv@Wm) + bias1 + histogram        (off arrays zeroed by memset)
//   P1 GEMM2(Wf->swizzled bf16) + bias2 + chunk-scan
//   P2 top-scan + Y-GEMM tiles [0,ya)
//   P3 scan-add/cursor + Y [ya,yb)
//   P4 permute + Y [yb,ytot)
//   P5 gather-average + epilogue (no LDS)
// ---------------------------------------------------------------------------

#define DD 256
#define SCAN_CHUNK 2048
#define NB 1024
#define NT 256

typedef __attribute__((ext_vector_type(8))) short short8;
typedef __attribute__((ext_vector_type(4))) float floatx4;

__device__ __forceinline__ short f2bf(float f) {
    union { float f; unsigned u; } c;
    c.f = f;
    unsigned r = c.u + 0x7fffu + ((c.u >> 16) & 1u);
    return (short)(r >> 16);
}
__device__ __forceinline__ float bflo(unsigned u) {
    union { unsigned u; float f; } c;
    c.u = u << 16;
    return c.f;
}
__device__ __forceinline__ float bfhi(unsigned u) {
    union { unsigned u; float f; } c;
    c.u = u & 0xffff0000u;
    return c.f;
}

// Device-scope grid barrier: monotonically increasing counter, zeroed by the
// host memset each iteration. All NB blocks are co-resident (grid==4/CU*256CU
// enforced by __launch_bounds__), so spin-wait cannot deadlock.
__device__ __forceinline__ void gbar(int* bar, int target) {
    __syncthreads();
    if (threadIdx.x == 0) {
        __threadfence();  // agent-scope release of this block's prior writes
        __hip_atomic_fetch_add(bar, 1, __ATOMIC_ACQ_REL, __HIP_MEMORY_SCOPE_AGENT);
        while (__hip_atomic_load(bar, __ATOMIC_ACQUIRE, __HIP_MEMORY_SCOPE_AGENT) < target)
            __builtin_amdgcn_s_sleep(8);
        __threadfence();  // acquire: invalidate stale L1/L2 before phase reads
    }
    __syncthreads();
}

// ---- Y-GEMM tile: 32 rows of Y = bf16(X) @ Wf (swizzled bf16 frags) --------
__device__ void ytile(int t, char* smem_,
                      const float* __restrict__ x_user, const float* __restrict__ x_game,
                      const short* __restrict__ Bswp, const short* __restrict__ Bswr,
                      short* __restrict__ Yp, short* __restrict__ Yr,
                      int n_user, int n_game, int nyb_u) {
    short (*As)[264] = (short(*)[264])smem_;
    const int tid = threadIdx.x;
    const int wave = tid >> 6;
    const int lane = tid & 63;
    const float* X;
    short* Y;
    const short* Bsw;
    int M, r0;
    if (t < nyb_u) { X = x_user; Y = Yp; Bsw = Bswp; M = n_user; r0 = t * 32; }
    else { X = x_game; Y = Yr; Bsw = Bswr; M = n_game; r0 = (t - nyb_u) * 32; }

#pragma unroll
    for (int j = 0; j < 8; ++j) {
        const int lr = wave * 8 + j;
        const int r = r0 + lr;
        short4 b4 = {0, 0, 0, 0};
        if (r < M) {
            const float4 v = ((const float4*)(X + (size_t)r * DD))[lane];
            b4.x = f2bf(v.x);
            b4.y = f2bf(v.y);
            b4.z = f2bf(v.z);
            b4.w = f2bf(v.w);
        }
        *(short4*)&As[lr][lane * 4] = b4;
    }
    __syncthreads();

    const int quad = lane >> 4;
    const int l16 = lane & 15;
    floatx4 cacc[2][4];
#pragma unroll
    for (int rt = 0; rt < 2; ++rt)
#pragma unroll
        for (int ct = 0; ct < 4; ++ct) cacc[rt][ct] = (floatx4){0.f, 0.f, 0.f, 0.f};

    for (int kb8 = 0; kb8 < 8; ++kb8) {
        short8 af[2];
#pragma unroll
        for (int rt = 0; rt < 2; ++rt)
            af[rt] = *(const short8*)&As[rt * 16 + l16][kb8 * 32 + quad * 8];
        short8 bf[4];
        const short* bp = Bsw + (((size_t)(kb8 * 16 + wave * 4) * 64 + lane) << 3);
#pragma unroll
        for (int ct = 0; ct < 4; ++ct)
            bf[ct] = *(const short8*)(bp + (ct << 9));
#pragma unroll
        for (int rt = 0; rt < 2; ++rt)
#pragma unroll
            for (int ct = 0; ct < 4; ++ct)
                cacc[rt][ct] = __builtin_amdgcn_mfma_f32_16x16x32_bf16(
                    af[rt], bf[ct], cacc[rt][ct], 0, 0, 0);
    }
    __syncthreads();

    // repack acc -> LDS (row-major bf16), then coalesced row stores
#pragma unroll
    for (int rt = 0; rt < 2; ++rt)
#pragma unroll
        for (int ct = 0; ct < 4; ++ct)
#pragma unroll
            for (int j = 0; j < 4; ++j)
                As[rt * 16 + quad * 4 + j][wave * 64 + ct * 16 + l16] =
                    f2bf(cacc[rt][ct][j]);
    __syncthreads();
#pragma unroll
    for (int j = 0; j < 8; ++j) {
        const int lr = wave * 8 + j;
        const int r = r0 + lr;
        if (r < M)
            *(short4*)(Y + (size_t)r * DD + lane * 4) = *(const short4*)&As[lr][lane * 4];
    }
    __syncthreads();  // guard As reuse by next tile iteration
}

// ---- gather-average + epilogue tile: 32 dst rows, no LDS -------------------
__device__ void aggtile(int t,
                        const short* __restrict__ Yp, const short* __restrict__ Yr,
                        const int* __restrict__ perm_rev, const int* __restrict__ off_user,
                        const float* __restrict__ bb_rev, const float* __restrict__ bout_user,
                        const int* __restrict__ perm_played, const int* __restrict__ off_game,
                        const float* __restrict__ bb_played, const float* __restrict__ bout_game,
                        const float* __restrict__ x_user, const float* __restrict__ x_game,
                        float* __restrict__ outp, int n_user, int n_game, int nbt_g) {
    const int tid = threadIdx.x;
    const int wave = tid >> 6;
    const int lane = tid & 63;
    const int n0 = lane * 4;

    const short* Y;
    const int* perm;
    const int* off;
    const float* bb;
    const float* bout;
    const float* x_res;
    float* out;
    int M, r0;
    if (t < nbt_g) {
        Y = Yp; perm = perm_played; off = off_game; bb = bb_played; bout = bout_game;
        x_res = x_game; out = outp + (size_t)n_user * DD; M = n_game; r0 = t * 32;
    } else {
        Y = Yr; perm = perm_rev; off = off_user; bb = bb_rev; bout = bout_user;
        x_res = x_user; out = outp; M = n_user; r0 = (t - nbt_g) * 32;
    }

    int e[8], en[8], deg[8];
    float4 acc[8];
#pragma unroll
    for (int j = 0; j < 8; ++j) {
        const int r = r0 + wave * 8 + j;
        e[j] = (r < M) ? off[r] : 0;
        en[j] = (r < M) ? off[r + 1] : 0;
        deg[j] = en[j] - e[j];
        acc[j].x = 0.f; acc[j].y = 0.f; acc[j].z = 0.f; acc[j].w = 0.f;
    }
    int mdeg = 0;
#pragma unroll
    for (int j = 0; j < 8; ++j) mdeg = max(mdeg, deg[j]);

    for (int it = 0; it < mdeg; ++it) {
        uint2 d[8];
        bool h[8];
#pragma unroll
        for (int j = 0; j < 8; ++j) {
            h[j] = e[j] < en[j];
            if (h[j]) {
                const int s = perm[e[j]++];
                d[j] = *(const uint2*)(Y + (size_t)s * DD + n0);
            }
        }
#pragma unroll
        for (int j = 0; j < 8; ++j) {
            if (h[j]) {
                acc[j].x += bflo(d[j].x);
                acc[j].y += bfhi(d[j].x);
                acc[j].z += bflo(d[j].y);
                acc[j].w += bfhi(d[j].y);
            }
        }
    }

    const float4 bbv = *(const float4*)(bb + n0);
    const float4 bov = *(const float4*)(bout + n0);
#pragma unroll
    for (int j = 0; j < 8; ++j) {
        const int r = r0 + wave * 8 + j;
        if (r < M) {
            const float inv = 1.0f / fmaxf((float)deg[j], 1.0f);
            const float beta = (deg[j] > 0) ? 1.0f : 0.0f;
            const float4 xr = *(const float4*)(x_res + (size_t)r * DD + n0);
            float4 o;
            o.x = fmaxf(acc[j].x * inv + beta * bbv.x + bov.x + xr.x, 0.f);
            o.y = fmaxf(acc[j].y * inv + beta * bbv.y + bov.y + xr.y, 0.f);
            o.z = fmaxf(acc[j].z * inv + beta * bbv.z + bov.z + xr.z, 0.f);
            o.w = fmaxf(acc[j].w * inv + beta * bbv.w + bov.w + xr.w, 0.f);
            *(float4*)(out + (size_t)r * DD + n0) = o;
        }
    }
}

// ---- the one persistent kernel ---------------------------------------------
__global__ __launch_bounds__(256, 4) void mega(
    const float* __restrict__ x_user, const float* __restrict__ x_game,
    const float* __restrict__ Wv_user, const float* __restrict__ bv_user,
    const float* __restrict__ Wout_user, const float* __restrict__ bout_user,
    const float* __restrict__ Wv_game, const float* __restrict__ bv_game,
    const float* __restrict__ Wout_game, const float* __restrict__ bout_game,
    const float* __restrict__ Wm_played, const float* __restrict__ bm_played,
    const float* __restrict__ Wm_rev, const float* __restrict__ bm_rev,
    const int* __restrict__ eps, const int* __restrict__ epd,
    const int* __restrict__ ers, const int* __restrict__ erd,
    int n_user, int n_game, int e_played, int e_rev,
    float* __restrict__ T0, float* __restrict__ T1,
    float* __restrict__ tv0, float* __restrict__ tv1,
    float* __restrict__ bb_played, float* __restrict__ bb_rev,
    short* __restrict__ Bsw_played, short* __restrict__ Bsw_rev,
    int* __restrict__ bar,
    int* __restrict__ off_game, int* __restrict__ off_user,
    int* __restrict__ cursor_game, int* __restrict__ cursor_user,
    int* __restrict__ sums_game, int* __restrict__ sums_user,
    int* __restrict__ perm_played, int* __restrict__ perm_rev,
    short* __restrict__ Yp, short* __restrict__ Yr,
    float* __restrict__ outp,
    int nbh_p, int nbh_r, int nch_g, int nch_u,
    int nyb_u, int nyb_g, int ya, int yb) {
    __shared__ __align__(16) char smem[32 * 264 * 2];  // 16896 B, phase-aliased
    float* fsm = (float*)smem;
    int* ism = (int*)smem;
    const int bid = blockIdx.x;
    const int tid = threadIdx.x;
    const int ytot = nyb_u + nyb_g;

    // ================= P0: GEMM1 (T=Wv@Wm x2) + bias1 + histogram ==========
    if (bid < 512) {
        const int which = bid >> 8;
        const int r = bid & 255;
        const float* A = which ? Wv_game : Wv_user;
        const float* B = which ? Wm_rev : Wm_played;
        float* C = which ? T1 : T0;
        fsm[tid] = A[r * DD + tid];
        __syncthreads();
        float acc = 0.f;
#pragma unroll 8
        for (int k = 0; k < DD; ++k) acc += fsm[k] * B[k * DD + tid];
        C[r * DD + tid] = acc;
    } else if (bid < 514) {
        const int w = bid - 512;
        const float* bv = w ? bv_game : bv_user;
        const float* Wm = w ? Wm_rev : Wm_played;
        const float* bm = w ? bm_rev : bm_played;
        float* tv = w ? tv1 : tv0;
        float acc = bm[tid];
#pragma unroll 8
        for (int k = 0; k < DD; ++k) acc += bv[k] * Wm[k * DD + tid];
        tv[tid] = acc;
    } else {
        for (int t = bid - 514; t < nbh_p + nbh_r; t += NB - 514) {
            if (t < nbh_p) {
                const int i = t * NT + tid;
                if (i < e_played) atomicAdd(&off_game[epd[i]], 1);
            } else {
                const int i = (t - nbh_p) * NT + tid;
                if (i < e_rev) atomicAdd(&off_user[erd[i]], 1);
            }
        }
    }
    gbar(bar, NB);

    // ================= P1: GEMM2 (Wf swizzled bf16) + bias2 + chunk-scan ===
    if (bid < 512) {
        const int which = bid >> 8;
        const int r = bid & 255;  // k index of Wf
        const float* A = which ? T1 : T0;
        const float* B = which ? Wout_user : Wout_game;
        short* C = which ? Bsw_rev : Bsw_played;
        fsm[tid] = A[r * DD + tid];
        __syncthreads();
        float acc = 0.f;
#pragma unroll 8
        for (int k = 0; k < DD; ++k) acc += fsm[k] * B[k * DD + tid];
        const int idx = ((((r >> 5) * 16 + (tid >> 4)) * 64 +
                          ((tid & 15) | (((r >> 3) & 3) << 4))) << 3) + (r & 7);
        C[idx] = f2bf(acc * 0.125f);
    } else if (bid < 514) {
        const int w = bid - 512;
        const float* tsrc = w ? tv1 : tv0;
        const float* Wo = w ? Wout_user : Wout_game;
        float* bb = w ? bb_rev : bb_played;
        float acc = 0.f;
#pragma unroll 8
        for (int k = 0; k < DD; ++k) acc += tsrc[k] * Wo[k * DD + tid];
        bb[tid] = acc * 0.125f;
    } else if (bid - 514 < nch_g + nch_u) {
        const int t = bid - 514;
        int* off;
        int* sums;
        int n, cb;
        if (t < nch_g) { off = off_game; sums = sums_game; n = n_game; cb = t; }
        else { off = off_user; sums = sums_user; n = n_user; cb = t - nch_g; }
        const int base = cb * SCAN_CHUNK + tid * 8;
        int v[8];
        int s = 0;
#pragma unroll
        for (int i = 0; i < 8; ++i) {
            const int idx = base + i;
            v[i] = (idx < n) ? off[idx] : 0;
            s += v[i];
        }
        ism[tid] = s;
        __syncthreads();
        for (int d = 1; d < 256; d <<= 1) {
            const int t2 = (tid >= d) ? ism[tid - d] : 0;
            __syncthreads();
            ism[tid] += t2;
            __syncthreads();
        }
        int excl = tid ? ism[tid - 1] : 0;
        if (tid == 255) sums[cb] = ism[255];
#pragma unroll
        for (int i = 0; i < 8; ++i) {
            const int idx = base + i;
            if (idx < n) off[idx] = excl;
            excl += v[i];
        }
    }
    gbar(bar, 2 * NB);

    // ================= P2: top-scan + Y tiles [0, ya) =======================
    if (bid < 2) {
        int* sums = bid ? sums_user : sums_game;
        const int nch = bid ? nch_u : nch_g;
        ism[tid] = (tid < nch) ? sums[tid] : 0;
        __syncthreads();
        for (int d = 1; d < 256; d <<= 1) {
            const int t2 = (tid >= d) ? ism[tid - d] : 0;
            __syncthreads();
            ism[tid] += t2;
            __syncthreads();
        }
        if (tid < nch) sums[tid] = tid ? ism[tid - 1] : 0;
        __syncthreads();
    }
    for (int t = bid; t < ya; t += NB)
        ytile(t, smem, x_user, x_game, Bsw_played, Bsw_rev, Yp, Yr,
              n_user, n_game, nyb_u);
    gbar(bar, 3 * NB);

    // ================= P3: scan-add + cursor init + Y [ya, yb) ==============
    {
        const int gidx = bid * NT + tid;
        const int span_g = n_game + 1;
        const int ntot = span_g + n_user + 1;
        if (gidx < ntot) {
            if (gidx < span_g) {
                if (gidx < n_game) {
                    const int v = off_game[gidx] + sums_game[gidx / SCAN_CHUNK];
                    off_game[gidx] = v;
                    cursor_game[gidx] = v;
                } else {
                    off_game[n_game] = e_played;
                }
            } else {
                const int idx = gidx - span_g;
                if (idx < n_user) {
                    const int v = off_user[idx] + sums_user[idx / SCAN_CHUNK];
                    off_user[idx] = v;
                    cursor_user[idx] = v;
                } else {
                    off_user[n_user] = e_rev;
                }
            }
        }
    }
    for (int t = ya + bid; t < yb; t += NB)
        ytile(t, smem, x_user, x_game, Bsw_played, Bsw_rev, Yp, Yr,
              n_user, n_game, nyb_u);
    gbar(bar, 4 * NB);

    // ================= P4: permute + Y [yb, ytot) ===========================
    for (int t = bid; t < nbh_p + nbh_r; t += NB) {
        if (t < nbh_p) {
            const int i = t * NT + tid;
            if (i < e_played) {
                const int pos = atomicAdd(&cursor_game[epd[i]], 1);
                perm_played[pos] = eps[i];
            }
        } else {
            const int i = (t - nbh_p) * NT + tid;
            if (i < e_rev) {
                const int pos = atomicAdd(&cursor_user[erd[i]], 1);
                perm_rev[pos] = ers[i];
            }
        }
    }
    for (int t = yb + bid; t < ytot; t += NB)
        ytile(t, smem, x_user, x_game, Bsw_played, Bsw_rev, Yp, Yr,
              n_user, n_game, nyb_u);
    gbar(bar, 5 * NB);

    // ================= P5: gather-average + epilogue ========================
    for (int t = bid; t < nyb_g + nyb_u; t += NB)
        aggtile(t, Yp, Yr, perm_rev, off_user, bb_rev, bout_user,
                perm_played, off_game, bb_played, bout_game,
                x_user, x_game, outp, n_user, n_game, nyb_g);
}

extern "C" void kernel_launch(void* const* d_in, const int* in_sizes, int n_in,
                              void* d_out, int out_size, void* d_ws, size_t ws_size,
                              hipStream_t stream) {
    const float* x_user = (const float*)d_in[0];
    const float* x_game = (const float*)d_in[1];
    const float* Wv_user = (const float*)d_in[6];
    const float* bv_user = (const float*)d_in[7];
    const float* Wout_user = (const float*)d_in[8];
    const float* bout_user = (const float*)d_in[9];
    const float* Wv_game = (const float*)d_in[14];
    const float* bv_game = (const float*)d_in[15];
    const float* Wout_game = (const float*)d_in[16];
    const float* bout_game = (const float*)d_in[17];
    const float* Wm_played = (const float*)d_in[20];
    const float* bm_played = (const float*)d_in[21];
    const float* Wm_rev = (const float*)d_in[24];
    const float* bm_rev = (const float*)d_in[25];
    const int* ei_played_src = (const int*)d_in[26];
    const int* ei_played_dst = (const int*)d_in[27];
    const int* ei_rev_src = (const int*)d_in[28];
    const int* ei_rev_dst = (const int*)d_in[29];

    const int n_user = in_sizes[0] / DD;
    const int n_game = in_sizes[1] / DD;
    const int e_played = in_sizes[26];
    const int e_rev = in_sizes[28];

    float* out = (float*)d_out;

    // ---- workspace layout ----
    float* fws = (float*)d_ws;
    float* T0 = fws;                       // 64K f32
    float* T1 = T0 + DD * DD;              // 64K f32
    float* bb_played = T1 + DD * DD;       // 256
    float* bb_rev = bb_played + DD;        // 256
    float* tv0 = bb_rev + DD;              // 256
    float* tv1 = tv0 + DD;                 // 256
    short* Bsw_played = (short*)(tv1 + DD);      // 64K bf16
    short* Bsw_rev = Bsw_played + DD * DD;       // 64K bf16
    int* iws = (int*)(Bsw_rev + DD * DD);
    int* bar = iws;                            // 8 ints (barrier counter)
    int* off_game = bar + 8;                   // n_game+1   } zeroed together
    int* off_user = off_game + (n_game + 1);   // n_user+1   } with bar
    int* cursor_game = off_user + (n_user + 1);
    int* cursor_user = cursor_game + n_game;
    int* sums_game = cursor_user + n_user;     // 256
    int* sums_user = sums_game + 256;          // 256
    int* perm_played = sums_user + 256;        // E
    int* perm_rev = perm_played + e_played;    // E
    uintptr_t yaddr = (uintptr_t)(perm_rev + e_rev);
    yaddr = (yaddr + 255) & ~(uintptr_t)255;
    short* Yp = (short*)yaddr;                 // n_user x 256 bf16 (51.2MB)
    short* Yr = Yp + (size_t)n_user * DD;      // n_game x 256 bf16 (25.6MB)
    (void)ws_size; (void)n_in; (void)out_size;

    const int nbh_p = (e_played + 255) / 256;
    const int nbh_r = (e_rev + 255) / 256;
    const int nch_g = (n_game + SCAN_CHUNK - 1) / SCAN_CHUNK;
    const int nch_u = (n_user + SCAN_CHUNK - 1) / SCAN_CHUNK;
    const int nyb_u = (n_user + 31) / 32;
    const int nyb_g = (n_game + 31) / 32;
    const int ytot = nyb_u + nyb_g;
    int ya = 1900; if (ya > ytot) ya = ytot;
    int yb = 3400; if (yb > ytot) yb = ytot;
    if (yb < ya) yb = ya;

    // zero: barrier counter + both histogram/offset arrays (contiguous)
    hipMemsetAsync(bar, 0, (size_t)(8 + (n_game + 1) + (n_user + 1)) * sizeof(int),
                   stream);

    mega<<<NB, NT, 0, stream>>>(
        x_user, x_game,
        Wv_user, bv_user, Wout_user, bout_user,
        Wv_game, bv_game, Wout_game, bout_game,
        Wm_played, bm_played, Wm_rev, bm_rev,
        ei_played_src, ei_played_dst, ei_rev_src, ei_rev_dst,
        n_user, n_game, e_played, e_rev,
        T0, T1, tv0, tv1, bb_played, bb_rev,
        Bsw_played, Bsw_rev,
        bar, off_game, off_user, cursor_game, cursor_user,
        sums_game, sums_user, perm_played, perm_rev,
        Yp, Yr, out,
        nbh_p, nbh_r, nch_g, nch_u, nyb_u, nyb_g, ya, yb);
}

// Round 4
// 484.041 us; speedup vs baseline: 3.4123x; 3.4123x over previous
//
#include <hip/hip_runtime.h>
#include <cstddef>
#include <cstdint>

// ---------------------------------------------------------------------------
// HGTConv, algebraically reduced:
//   softmax(scores).mean(-1) == 1/8 exactly  =>  attention path is dead code.
//   out = relu( mx @ (Wv@Wm@Wout)/8 + beta*((bv@Wm+bm)@Wout)/8 + bout + x )
//   with mx = segsum(x[src])/max(cnt,1), beta = (cnt>0).
//
// R6: revert persistent kernel (R5 post-mortem: residual ~200us is FIXED
// harness overhead, and device-scope spin atomics force L2 invalidations on
// non-coherent per-XCD L2s -> 450 GB/s collapse). Back to R1's fused
// aggregate+GEMM structure, plus DEGREE-SORTED row processing:
//   - fuseB: per-chunk degree histogram (reversed 64-bin key) + deg8 array
//   - fuseC: 128-bin scan -> bin cursors
//   - fuseD: block-aggregated counting-sort scatter -> rowperm (desc degree)
//   - agg_gemm4: waves gather rows of near-uniform degree => rounds ~= mean
//     degree (was max-of-8), all 8 load chains stay live, no wave straggle.
// ---------------------------------------------------------------------------

#define DD 256
#define SCAN_CHUNK 2048

typedef __attribute__((ext_vector_type(8))) short short8;
typedef __attribute__((ext_vector_type(4))) float floatx4;

__device__ __forceinline__ short f2bf(float f) {
    union { float f; unsigned u; } c;
    c.f = f;
    unsigned r = c.u + 0x7fffu + ((c.u >> 16) & 1u);
    return (short)(r >> 16);
}

// ---- fused launch A: weight GEMM stage 1 (T = Wv@Wm, x2) + both histograms
__global__ __launch_bounds__(256) void fuseA(const float* __restrict__ A0,
                                             const float* __restrict__ B0,
                                             float* __restrict__ C0,
                                             const float* __restrict__ A1,
                                             const float* __restrict__ B1,
                                             float* __restrict__ C1,
                                             const int* __restrict__ dst0,
                                             int* __restrict__ cnt0, int E0,
                                             const int* __restrict__ dst1,
                                             int* __restrict__ cnt1, int E1) {
    __shared__ float As[DD];
    const int bid = blockIdx.x;
    const int c = threadIdx.x;
    if (bid < 512) {
        const int which = bid >> 8;
        const int r = bid & 255;
        const float* A = which ? A1 : A0;
        const float* B = which ? B1 : B0;
        float* C = which ? C1 : C0;
        As[c] = A[r * DD + c];
        __syncthreads();
        float acc = 0.f;
#pragma unroll 8
        for (int k = 0; k < DD; ++k) acc += As[k] * B[k * DD + c];
        C[r * DD + c] = acc;
    } else {
        const int nb0 = (E0 + 255) >> 8;
        const int b = bid - 512;
        if (b < nb0) {
            const int i = b * 256 + c;
            if (i < E0) atomicAdd(&cnt0[dst0[i]], 1);
        } else {
            const int i = (b - nb0) * 256 + c;
            if (i < E1) atomicAdd(&cnt1[dst1[i]], 1);
        }
    }
}

// ---- fused launch B: Wf = T@Wout*0.125 -> swizzled bf16 (x2) + scan_chunk(x2)
//      + degree capture (deg8) + reversed-key degree histogram (dbin[128]).
// Bsw layout: Bsw[((k>>5)*16 + (n>>4))*64 + ((n&15)|(((k>>3)&3)<<4))][k&7]
__global__ __launch_bounds__(256) void fuseB(const float* __restrict__ A0,
                                             const float* __restrict__ B0,
                                             short* __restrict__ C0,
                                             const float* __restrict__ A1,
                                             const float* __restrict__ B1,
                                             short* __restrict__ C1,
                                             int* __restrict__ off_g,
                                             int* __restrict__ sums_g, int n_g,
                                             int* __restrict__ off_u,
                                             int* __restrict__ sums_u, int n_u,
                                             unsigned char* __restrict__ deg8,
                                             int* __restrict__ dbin) {
    __shared__ float As[DD];
    __shared__ int ls[256];
    __shared__ int lhist[64];
    const int bid = blockIdx.x;
    const int tid = threadIdx.x;
    if (bid < 512) {
        const int which = bid >> 8;
        const int r = bid & 255;  // k index of Wf
        const int c = tid;        // n index of Wf
        const float* A = which ? A1 : A0;
        const float* B = which ? B1 : B0;
        short* C = which ? C1 : C0;
        As[c] = A[r * DD + c];
        __syncthreads();
        float acc = 0.f;
#pragma unroll 8
        for (int k = 0; k < DD; ++k) acc += As[k] * B[k * DD + c];
        const int idx = ((((r >> 5) * 16 + (c >> 4)) * 64 +
                          ((c & 15) | (((r >> 3) & 3) << 4))) << 3) + (r & 7);
        C[idx] = f2bf(acc * 0.125f);
    } else {
        const int nch_g = (n_g + SCAN_CHUNK - 1) / SCAN_CHUNK;
        const int b = bid - 512;
        int* off;
        int* sums;
        int n, cb, degbase, dbbase;
        if (b < nch_g) {
            off = off_g; sums = sums_g; n = n_g; cb = b; degbase = 0; dbbase = 0;
        } else {
            off = off_u; sums = sums_u; n = n_u; cb = b - nch_g;
            degbase = n_g; dbbase = 64;
        }
        if (tid < 64) lhist[tid] = 0;
        const int base = cb * SCAN_CHUNK + tid * 8;
        int v[8];
        int s = 0;
#pragma unroll
        for (int i = 0; i < 8; ++i) {
            const int idx = base + i;
            v[i] = (idx < n) ? off[idx] : 0;
            s += v[i];
        }
        ls[tid] = s;
        __syncthreads();
        // degree capture + local histogram (reversed key: high degree -> bin 0)
#pragma unroll
        for (int i = 0; i < 8; ++i) {
            const int idx = base + i;
            if (idx < n) {
                const int d = v[i];
                deg8[degbase + idx] = (unsigned char)(d > 255 ? 255 : d);
                const int bin = 63 - (d > 63 ? 63 : d);
                atomicAdd(&lhist[bin], 1);
            }
        }
        for (int d = 1; d < 256; d <<= 1) {
            const int t = (tid >= d) ? ls[tid - d] : 0;
            __syncthreads();
            ls[tid] += t;
            __syncthreads();
        }
        int excl = tid ? ls[tid - 1] : 0;
        if (tid == 255) sums[cb] = ls[255];
#pragma unroll
        for (int i = 0; i < 8; ++i) {
            const int idx = base + i;
            if (idx < n) off[idx] = excl;
            excl += v[i];
        }
        __syncthreads();
        if (tid < 64 && lhist[tid]) atomicAdd(&dbin[dbbase + tid], lhist[tid]);
    }
}

// ---- fused launch C: bias fusion (2) + scan_sums (2) + degree-bin scan (1)
__global__ __launch_bounds__(256) void fuseC(const float* __restrict__ bv0,
                                             const float* __restrict__ Wm0,
                                             const float* __restrict__ bm0,
                                             const float* __restrict__ Wout0,
                                             float* __restrict__ bb0,
                                             const float* __restrict__ bv1,
                                             const float* __restrict__ Wm1,
                                             const float* __restrict__ bm1,
                                             const float* __restrict__ Wout1,
                                             float* __restrict__ bb1,
                                             int* __restrict__ sums_g, int nch_g,
                                             int* __restrict__ sums_u, int nch_u,
                                             const int* __restrict__ dbin,
                                             int* __restrict__ dcur) {
    __shared__ float t[DD];
    __shared__ int ls[256];
    const int tid = threadIdx.x;
    if (blockIdx.x < 2) {
        const int w = blockIdx.x;
        const float* bv = w ? bv1 : bv0;
        const float* Wm = w ? Wm1 : Wm0;
        const float* bm = w ? bm1 : bm0;
        const float* Wout = w ? Wout1 : Wout0;
        float* bb = w ? bb1 : bb0;
        float acc = bm[tid];
#pragma unroll 8
        for (int k = 0; k < DD; ++k) acc += bv[k] * Wm[k * DD + tid];
        t[tid] = acc;
        __syncthreads();
        float acc2 = 0.f;
#pragma unroll 8
        for (int k = 0; k < DD; ++k) acc2 += t[k] * Wout[k * DD + tid];
        bb[tid] = acc2 * 0.125f;
    } else if (blockIdx.x < 4) {
        int* sums = (blockIdx.x == 2) ? sums_g : sums_u;
        const int nch = (blockIdx.x == 2) ? nch_g : nch_u;
        ls[tid] = (tid < nch) ? sums[tid] : 0;
        __syncthreads();
        for (int d = 1; d < 256; d <<= 1) {
            const int t2 = (tid >= d) ? ls[tid - d] : 0;
            __syncthreads();
            ls[tid] += t2;
            __syncthreads();
        }
        if (tid < nch) sums[tid] = tid ? ls[tid - 1] : 0;
    } else {
        // exclusive scan of dbin[128], restarting at each 64-bin half
        ls[tid] = (tid < 128) ? dbin[tid] : 0;
        __syncthreads();
        for (int d = 1; d < 64; d <<= 1) {
            const int t2 = ((tid & 63) >= d) ? ls[tid - d] : 0;
            __syncthreads();
            ls[tid] += t2;
            __syncthreads();
        }
        if (tid < 128) dcur[tid] = (tid & 63) ? ls[tid - 1] : 0;
    }
}

// ---- fused launch D: scan_add(x2) + cursor init + counting-sort scatter ----
__global__ __launch_bounds__(256) void fuseD(int* __restrict__ off_g,
                                             const int* __restrict__ sums_g,
                                             int* __restrict__ cur_g, int n_g, int Eg,
                                             int* __restrict__ off_u,
                                             const int* __restrict__ sums_u,
                                             int* __restrict__ cur_u, int n_u, int Eu,
                                             const unsigned char* __restrict__ deg8,
                                             int* __restrict__ dcur,
                                             int* __restrict__ rowperm_g,
                                             int* __restrict__ rowperm_u) {
    __shared__ int lh[128];
    __shared__ int lb[128];
    const int tid = threadIdx.x;
    const int gidx = blockIdx.x * 256 + tid;
    const int span_g = n_g + 1;
    if (tid < 128) lh[tid] = 0;
    __syncthreads();

    int bin = -1, rowid = -1, rank = 0;
    if (gidx < span_g) {
        if (gidx < n_g) {
            const int v = off_g[gidx] + sums_g[gidx / SCAN_CHUNK];
            off_g[gidx] = v;
            cur_g[gidx] = v;
            const int d = deg8[gidx];
            bin = 63 - (d > 63 ? 63 : d);
            rowid = gidx;
        } else {
            off_g[n_g] = Eg;
        }
    } else {
        const int idx = gidx - span_g;
        if (idx < n_u) {
            const int v = off_u[idx] + sums_u[idx / SCAN_CHUNK];
            off_u[idx] = v;
            cur_u[idx] = v;
            const int d = deg8[n_g + idx];
            bin = 64 + 63 - (d > 63 ? 63 : d);
            rowid = idx;
        } else if (idx == n_u) {
            off_u[n_u] = Eu;
        }
    }
    if (bin >= 0) rank = atomicAdd(&lh[bin], 1);
    __syncthreads();
    if (tid < 128 && lh[tid]) lb[tid] = atomicAdd(&dcur[tid], lh[tid]);
    __syncthreads();
    if (bin >= 0) {
        const int pos = lb[bin] + rank;
        if (bin < 64) rowperm_g[pos] = rowid;
        else rowperm_u[pos] = rowid;
    }
}

// ---- fused launch E: permute (x2)
__global__ __launch_bounds__(256) void fuseE(const int* __restrict__ src0,
                                             const int* __restrict__ dst0,
                                             int* __restrict__ cur0,
                                             int* __restrict__ perm0, int E0,
                                             const int* __restrict__ src1,
                                             const int* __restrict__ dst1,
                                             int* __restrict__ cur1,
                                             int* __restrict__ perm1, int E1) {
    const int nb0 = (E0 + 255) >> 8;
    const int b = blockIdx.x;
    const int tid = threadIdx.x;
    if (b < nb0) {
        const int i = b * 256 + tid;
        if (i < E0) {
            const int pos = atomicAdd(&cur0[dst0[i]], 1);
            perm0[pos] = src0[i];
        }
    } else {
        const int i = (b - nb0) * 256 + tid;
        if (i < E1) {
            const int pos = atomicAdd(&cur1[dst1[i]], 1);
            perm1[pos] = src1[i];
        }
    }
}

// ---- fused aggregate + bf16-MFMA GEMM + epilogue, degree-sorted rows -------
// Block = 32 sorted dst rows (via rowperm), 256 threads (4 waves).
// Phase 1: wave owns 8 rows of near-uniform degree (sorted) => round count
//          ~= mean degree, 8 load chains live every round, no wave straggle.
// Phase 2: wave w computes rows[0:32) x cols[w*64, w*64+64), 16x16x32 MFMA.
__global__ __launch_bounds__(256, 4) void agg_gemm4(
    const float* __restrict__ x_user, const float* __restrict__ x_game,
    const int* __restrict__ perm_rev, const int* __restrict__ off_user,
    const short* __restrict__ Bsw_rev, const float* __restrict__ bb_rev,
    const float* __restrict__ bout_user, const int* __restrict__ rowperm_u,
    const int* __restrict__ perm_played, const int* __restrict__ off_game,
    const short* __restrict__ Bsw_played, const float* __restrict__ bb_played,
    const float* __restrict__ bout_game, const int* __restrict__ rowperm_g,
    float* __restrict__ outp, int n_user, int n_game, int nb_game) {
    __shared__ short As[32][264];
    __shared__ float bt[32];
    __shared__ int rsh[32];

    const int tid = threadIdx.x;
    const int wave = __builtin_amdgcn_readfirstlane(tid >> 6);
    const int lane = tid & 63;

    const float* x_src;
    const float* x_res;
    const int* perm;
    const int* off;
    const short* Bsw;
    const float* bb;
    const float* bout;
    const int* rperm;
    float* out;
    int M, r0;
    if ((int)blockIdx.x < nb_game) {
        // game pass first (deeper degrees; sorted heavy bins lead)
        x_src = x_user; x_res = x_game;
        perm = perm_played; off = off_game;
        Bsw = Bsw_played; bb = bb_played; bout = bout_game;
        rperm = rowperm_g;
        out = outp + (size_t)n_user * DD;
        M = n_game;
        r0 = (int)blockIdx.x * 32;
    } else {
        x_src = x_game; x_res = x_user;
        perm = perm_rev; off = off_user;
        Bsw = Bsw_rev; bb = bb_rev; bout = bout_user;
        rperm = rowperm_u;
        out = outp;
        M = n_user;
        r0 = ((int)blockIdx.x - nb_game) * 32;
    }

    // ---- phase 1: interleaved gather over sorted rows ----
    int e[8], en[8], deg[8];
    float4 acc[8];
#pragma unroll
    for (int j = 0; j < 8; ++j) {
        const int slot = r0 + wave * 8 + j;
        const int rs = (slot < M) ? rperm[slot] : -1;
        e[j] = (rs >= 0) ? off[rs] : 0;
        en[j] = (rs >= 0) ? off[rs + 1] : 0;
        deg[j] = en[j] - e[j];
        acc[j].x = 0.f; acc[j].y = 0.f; acc[j].z = 0.f; acc[j].w = 0.f;
        if (lane == 0) {
            const int lr = wave * 8 + j;
            rsh[lr] = rs;
            bt[lr] = (deg[j] > 0) ? 1.0f : 0.0f;
        }
    }
    int mdeg = 0;
#pragma unroll
    for (int j = 0; j < 8; ++j) mdeg = max(mdeg, deg[j]);

    for (int t = 0; t < mdeg; ++t) {
        float4 v[8];
        bool h[8];
#pragma unroll
        for (int j = 0; j < 8; ++j) {
            h[j] = e[j] < en[j];
            if (h[j]) {
                const int s = perm[e[j]++];
                v[j] = ((const float4*)(x_src + (size_t)s * DD))[lane];
            }
        }
#pragma unroll
        for (int j = 0; j < 8; ++j) {
            if (h[j]) {
                acc[j].x += v[j].x;
                acc[j].y += v[j].y;
                acc[j].z += v[j].z;
                acc[j].w += v[j].w;
            }
        }
    }
#pragma unroll
    for (int j = 0; j < 8; ++j) {
        const int lr = wave * 8 + j;
        const float inv = 1.0f / fmaxf((float)deg[j], 1.0f);
        short4 b4;
        b4.x = f2bf(acc[j].x * inv);
        b4.y = f2bf(acc[j].y * inv);
        b4.z = f2bf(acc[j].z * inv);
        b4.w = f2bf(acc[j].w * inv);
        *(short4*)&As[lr][lane * 4] = b4;
    }
    __syncthreads();

    // ---- phase 2: MFMA, 32 rows x 64 cols per wave ----
    const int quad = lane >> 4;
    const int l16 = lane & 15;
    floatx4 cacc[2][4];
#pragma unroll
    for (int rt = 0; rt < 2; ++rt)
#pragma unroll
        for (int ct = 0; ct < 4; ++ct) cacc[rt][ct] = (floatx4){0.f, 0.f, 0.f, 0.f};

    for (int kb8 = 0; kb8 < 8; ++kb8) {
        short8 af[2];
#pragma unroll
        for (int rt = 0; rt < 2; ++rt)
            af[rt] = *(const short8*)&As[rt * 16 + l16][kb8 * 32 + quad * 8];
        short8 bf[4];
        const short* bp = Bsw + (((size_t)(kb8 * 16 + wave * 4) * 64 + lane) << 3);
#pragma unroll
        for (int ct = 0; ct < 4; ++ct)
            bf[ct] = *(const short8*)(bp + (ct << 9));
#pragma unroll
        for (int rt = 0; rt < 2; ++rt)
#pragma unroll
            for (int ct = 0; ct < 4; ++ct)
                cacc[rt][ct] = __builtin_amdgcn_mfma_f32_16x16x32_bf16(
                    af[rt], bf[ct], cacc[rt][ct], 0, 0, 0);
    }

    // ---- epilogue ----
    float bbv[4], bov[4];
#pragma unroll
    for (int ct = 0; ct < 4; ++ct) {
        const int n = wave * 64 + ct * 16 + l16;
        bbv[ct] = bb[n];
        bov[ct] = bout[n];
    }
#pragma unroll
    for (int rt = 0; rt < 2; ++rt) {
#pragma unroll
        for (int j = 0; j < 4; ++j) {
            const int lr = rt * 16 + quad * 4 + j;
            if (r0 + lr < M) {
                const int rs = rsh[lr];
                const float btv = bt[lr];
                const float* xr = x_res + (size_t)rs * DD;
                float* orow = out + (size_t)rs * DD;
#pragma unroll
                for (int ct = 0; ct < 4; ++ct) {
                    const int n = wave * 64 + ct * 16 + l16;
                    const float o = cacc[rt][ct][j] + btv * bbv[ct] + bov[ct] + xr[n];
                    orow[n] = fmaxf(o, 0.f);
                }
            }
        }
    }
}

extern "C" void kernel_launch(void* const* d_in, const int* in_sizes, int n_in,
                              void* d_out, int out_size, void* d_ws, size_t ws_size,
                              hipStream_t stream) {
    const float* x_user = (const float*)d_in[0];
    const float* x_game = (const float*)d_in[1];
    const float* Wv_user = (const float*)d_in[6];
    const float* bv_user = (const float*)d_in[7];
    const float* Wout_user = (const float*)d_in[8];
    const float* bout_user = (const float*)d_in[9];
    const float* Wv_game = (const float*)d_in[14];
    const float* bv_game = (const float*)d_in[15];
    const float* Wout_game = (const float*)d_in[16];
    const float* bout_game = (const float*)d_in[17];
    const float* Wm_played = (const float*)d_in[20];
    const float* bm_played = (const float*)d_in[21];
    const float* Wm_rev = (const float*)d_in[24];
    const float* bm_rev = (const float*)d_in[25];
    const int* ei_played_src = (const int*)d_in[26];
    const int* ei_played_dst = (const int*)d_in[27];
    const int* ei_rev_src = (const int*)d_in[28];
    const int* ei_rev_dst = (const int*)d_in[29];

    const int n_user = in_sizes[0] / DD;
    const int n_game = in_sizes[1] / DD;
    const int e_played = in_sizes[26];
    const int e_rev = in_sizes[28];

    float* out = (float*)d_out;

    // ---- workspace layout ----
    float* fws = (float*)d_ws;
    float* T0 = fws;                       // 64K f32
    float* T1 = T0 + DD * DD;              // 64K f32
    float* bb_played = T1 + DD * DD;       // 256
    float* bb_rev = bb_played + DD;        // 256
    short* Bsw_played = (short*)(bb_rev + DD);   // 64K bf16
    short* Bsw_rev = Bsw_played + DD * DD;       // 64K bf16
    int* iws = (int*)(Bsw_rev + DD * DD);
    int* dbin = iws;                           // 128  } zeroed
    int* off_game = dbin + 128;                // n_game+1 } together
    int* off_user = off_game + (n_game + 1);   // n_user+1 } by memset
    int* dcur = off_user + (n_user + 1);       // 128
    int* cursor_game = dcur + 128;
    int* cursor_user = cursor_game + n_game;
    int* sums_game = cursor_user + n_user;     // 256
    int* sums_user = sums_game + 256;          // 256
    int* perm_played = sums_user + 256;        // E
    int* perm_rev = perm_played + e_played;    // E
    int* rowperm_g = perm_rev + e_rev;         // n_game
    int* rowperm_u = rowperm_g + n_game;       // n_user
    unsigned char* deg8 = (unsigned char*)(rowperm_u + n_user);  // n_game+n_user
    (void)ws_size; (void)n_in; (void)out_size;

    // ---- zero: dbin + both histogram/offset arrays (contiguous) ----
    hipMemsetAsync(dbin, 0, (size_t)(128 + (n_game + 1) + (n_user + 1)) * sizeof(int),
                   stream);

    const int nbh_p = (e_played + 255) / 256;
    const int nbh_r = (e_rev + 255) / 256;
    const int nch_g = (n_game + SCAN_CHUNK - 1) / SCAN_CHUNK;
    const int nch_u = (n_user + SCAN_CHUNK - 1) / SCAN_CHUNK;

    // A: weight GEMM stage1 + histograms
    fuseA<<<512 + nbh_p + nbh_r, 256, 0, stream>>>(
        Wv_user, Wm_played, T0, Wv_game, Wm_rev, T1,
        ei_played_dst, off_game, e_played, ei_rev_dst, off_user, e_rev);
    // B: weight GEMM stage2 + chunk scans + degree capture/histogram
    fuseB<<<512 + nch_g + nch_u, 256, 0, stream>>>(
        T0, Wout_game, Bsw_played, T1, Wout_user, Bsw_rev,
        off_game, sums_game, n_game, off_user, sums_user, n_user,
        deg8, dbin);
    // C: bias fusion + chunk-sum scans + degree-bin scan
    fuseC<<<5, 256, 0, stream>>>(
        bv_user, Wm_played, bm_played, Wout_game, bb_played,
        bv_game, Wm_rev, bm_rev, Wout_user, bb_rev,
        sums_game, nch_g, sums_user, nch_u, dbin, dcur);
    // D: scan finalize + cursor init + counting-sort scatter
    const int ntot = (n_game + 1) + (n_user + 1);
    fuseD<<<(ntot + 255) / 256, 256, 0, stream>>>(
        off_game, sums_game, cursor_game, n_game, e_played,
        off_user, sums_user, cursor_user, n_user, e_rev,
        deg8, dcur, rowperm_g, rowperm_u);
    // E: permute both edge lists
    fuseE<<<nbh_p + nbh_r, 256, 0, stream>>>(
        ei_played_src, ei_played_dst, cursor_game, perm_played, e_played,
        ei_rev_src, ei_rev_dst, cursor_user, perm_rev, e_rev);

    // ---- fused aggregate + GEMM + epilogue, degree-sorted rows ----
    const int nb_game = (n_game + 31) / 32;
    const int nb_user = (n_user + 31) / 32;
    agg_gemm4<<<nb_game + nb_user, 256, 0, stream>>>(
        x_user, x_game, perm_rev, off_user, Bsw_rev, bb_rev, bout_user, rowperm_u,
        perm_played, off_game, Bsw_played, bb_played, bout_game, rowperm_g,
        out, n_user, n_game, nb_game);
}

// Round 5
// 469.882 us; speedup vs baseline: 3.5151x; 1.0301x over previous
//
#include <hip/hip_runtime.h>
#include <cstddef>
#include <cstdint>

// ---------------------------------------------------------------------------
// HGTConv, algebraically reduced:
//   softmax(scores).mean(-1) == 1/8 exactly  =>  attention path is dead code.
//   out = relu( mx @ (Wv@Wm@Wout)/8 + beta*((bv@Wm+bm)@Wout)/8 + bout + x )
//   with mx = segsum(x[src])/max(cnt,1), beta = (cnt>0).
//
// R7: revert R6's degree sort (scattered epilogue cost >= straggle gain;
// prediction failed -> straggle was not the bottleneck). True bottleneck
// (consistent across R0/R1/R2/R6 counters): the gather round serializes
// TWO dependent memory latencies -- perm[e] load, THEN row load. Fix:
// 2-deep software pipeline of the perm index stream (s0/s1/s2 registers);
// row loads issue first (oldest in vmcnt FIFO), perm prefetch for t+2
// stays outstanding during the accumulate, so each round pays only the
// row-load latency, overlapped 8-wide per wave x ~21 waves/CU.
// ---------------------------------------------------------------------------

#define DD 256
#define SCAN_CHUNK 2048

typedef __attribute__((ext_vector_type(8))) short short8;
typedef __attribute__((ext_vector_type(4))) float floatx4;

__device__ __forceinline__ short f2bf(float f) {
    union { float f; unsigned u; } c;
    c.f = f;
    unsigned r = c.u + 0x7fffu + ((c.u >> 16) & 1u);
    return (short)(r >> 16);
}

// ---- fused launch A: weight GEMM stage 1 (T = Wv@Wm, x2) + both histograms
__global__ __launch_bounds__(256) void fuseA(const float* __restrict__ A0,
                                             const float* __restrict__ B0,
                                             float* __restrict__ C0,
                                             const float* __restrict__ A1,
                                             const float* __restrict__ B1,
                                             float* __restrict__ C1,
                                             const int* __restrict__ dst0,
                                             int* __restrict__ cnt0, int E0,
                                             const int* __restrict__ dst1,
                                             int* __restrict__ cnt1, int E1) {
    __shared__ float As[DD];
    const int bid = blockIdx.x;
    const int c = threadIdx.x;
    if (bid < 512) {
        const int which = bid >> 8;
        const int r = bid & 255;
        const float* A = which ? A1 : A0;
        const float* B = which ? B1 : B0;
        float* C = which ? C1 : C0;
        As[c] = A[r * DD + c];
        __syncthreads();
        float acc = 0.f;
#pragma unroll 8
        for (int k = 0; k < DD; ++k) acc += As[k] * B[k * DD + c];
        C[r * DD + c] = acc;
    } else {
        const int nb0 = (E0 + 255) >> 8;
        const int b = bid - 512;
        if (b < nb0) {
            const int i = b * 256 + c;
            if (i < E0) atomicAdd(&cnt0[dst0[i]], 1);
        } else {
            const int i = (b - nb0) * 256 + c;
            if (i < E1) atomicAdd(&cnt1[dst1[i]], 1);
        }
    }
}

// ---- fused launch B: Wf = T@Wout*0.125 -> swizzled bf16 (x2) + scan_chunk(x2)
// Bsw layout: Bsw[((k>>5)*16 + (n>>4))*64 + ((n&15)|(((k>>3)&3)<<4))][k&7]
__global__ __launch_bounds__(256) void fuseB(const float* __restrict__ A0,
                                             const float* __restrict__ B0,
                                             short* __restrict__ C0,
                                             const float* __restrict__ A1,
                                             const float* __restrict__ B1,
                                             short* __restrict__ C1,
                                             int* __restrict__ off_g,
                                             int* __restrict__ sums_g, int n_g,
                                             int* __restrict__ off_u,
                                             int* __restrict__ sums_u, int n_u) {
    __shared__ float As[DD];
    __shared__ int ls[256];
    const int bid = blockIdx.x;
    const int tid = threadIdx.x;
    if (bid < 512) {
        const int which = bid >> 8;
        const int r = bid & 255;  // k index of Wf
        const int c = tid;        // n index of Wf
        const float* A = which ? A1 : A0;
        const float* B = which ? B1 : B0;
        short* C = which ? C1 : C0;
        As[c] = A[r * DD + c];
        __syncthreads();
        float acc = 0.f;
#pragma unroll 8
        for (int k = 0; k < DD; ++k) acc += As[k] * B[k * DD + c];
        const int idx = ((((r >> 5) * 16 + (c >> 4)) * 64 +
                          ((c & 15) | (((r >> 3) & 3) << 4))) << 3) + (r & 7);
        C[idx] = f2bf(acc * 0.125f);
    } else {
        const int nch_g = (n_g + SCAN_CHUNK - 1) / SCAN_CHUNK;
        const int b = bid - 512;
        int* off;
        int* sums;
        int n, cb;
        if (b < nch_g) { off = off_g; sums = sums_g; n = n_g; cb = b; }
        else { off = off_u; sums = sums_u; n = n_u; cb = b - nch_g; }
        const int base = cb * SCAN_CHUNK + tid * 8;
        int v[8];
        int s = 0;
#pragma unroll
        for (int i = 0; i < 8; ++i) {
            const int idx = base + i;
            v[i] = (idx < n) ? off[idx] : 0;
            s += v[i];
        }
        ls[tid] = s;
        __syncthreads();
        for (int d = 1; d < 256; d <<= 1) {
            const int t = (tid >= d) ? ls[tid - d] : 0;
            __syncthreads();
            ls[tid] += t;
            __syncthreads();
        }
        int excl = tid ? ls[tid - 1] : 0;
        if (tid == 255) sums[cb] = ls[255];
#pragma unroll
        for (int i = 0; i < 8; ++i) {
            const int idx = base + i;
            if (idx < n) off[idx] = excl;
            excl += v[i];
        }
    }
}

// ---- fused launch C: bias fusion (2 blocks) + scan_sums (2 blocks)
__global__ __launch_bounds__(256) void fuseC(const float* __restrict__ bv0,
                                             const float* __restrict__ Wm0,
                                             const float* __restrict__ bm0,
                                             const float* __restrict__ Wout0,
                                             float* __restrict__ bb0,
                                             const float* __restrict__ bv1,
                                             const float* __restrict__ Wm1,
                                             const float* __restrict__ bm1,
                                             const float* __restrict__ Wout1,
                                             float* __restrict__ bb1,
                                             int* __restrict__ sums_g, int nch_g,
                                             int* __restrict__ sums_u, int nch_u) {
    __shared__ float t[DD];
    __shared__ int ls[256];
    const int tid = threadIdx.x;
    if (blockIdx.x < 2) {
        const int w = blockIdx.x;
        const float* bv = w ? bv1 : bv0;
        const float* Wm = w ? Wm1 : Wm0;
        const float* bm = w ? bm1 : bm0;
        const float* Wout = w ? Wout1 : Wout0;
        float* bb = w ? bb1 : bb0;
        float acc = bm[tid];
#pragma unroll 8
        for (int k = 0; k < DD; ++k) acc += bv[k] * Wm[k * DD + tid];
        t[tid] = acc;
        __syncthreads();
        float acc2 = 0.f;
#pragma unroll 8
        for (int k = 0; k < DD; ++k) acc2 += t[k] * Wout[k * DD + tid];
        bb[tid] = acc2 * 0.125f;
    } else {
        int* sums = (blockIdx.x == 2) ? sums_g : sums_u;
        const int nch = (blockIdx.x == 2) ? nch_g : nch_u;
        ls[tid] = (tid < nch) ? sums[tid] : 0;
        __syncthreads();
        for (int d = 1; d < 256; d <<= 1) {
            const int t2 = (tid >= d) ? ls[tid - d] : 0;
            __syncthreads();
            ls[tid] += t2;
            __syncthreads();
        }
        if (tid < nch) sums[tid] = tid ? ls[tid - 1] : 0;
    }
}

// ---- fused launch D: scan_add(x2) + cursor init (replaces 2 memcpys)
__global__ __launch_bounds__(256) void fuseD(int* __restrict__ off_g,
                                             const int* __restrict__ sums_g,
                                             int* __restrict__ cur_g, int n_g, int Eg,
                                             int* __restrict__ off_u,
                                             const int* __restrict__ sums_u,
                                             int* __restrict__ cur_u, int n_u, int Eu) {
    const int gidx = blockIdx.x * 256 + threadIdx.x;
    const int span_g = n_g + 1;
    if (gidx < span_g) {
        if (gidx < n_g) {
            const int v = off_g[gidx] + sums_g[gidx / SCAN_CHUNK];
            off_g[gidx] = v;
            cur_g[gidx] = v;
        } else {
            off_g[n_g] = Eg;
        }
    } else {
        const int idx = gidx - span_g;
        if (idx < n_u) {
            const int v = off_u[idx] + sums_u[idx / SCAN_CHUNK];
            off_u[idx] = v;
            cur_u[idx] = v;
        } else if (idx == n_u) {
            off_u[n_u] = Eu;
        }
    }
}

// ---- fused launch E: permute (x2)
__global__ __launch_bounds__(256) void fuseE(const int* __restrict__ src0,
                                             const int* __restrict__ dst0,
                                             int* __restrict__ cur0,
                                             int* __restrict__ perm0, int E0,
                                             const int* __restrict__ src1,
                                             const int* __restrict__ dst1,
                                             int* __restrict__ cur1,
                                             int* __restrict__ perm1, int E1) {
    const int nb0 = (E0 + 255) >> 8;
    const int b = blockIdx.x;
    const int tid = threadIdx.x;
    if (b < nb0) {
        const int i = b * 256 + tid;
        if (i < E0) {
            const int pos = atomicAdd(&cur0[dst0[i]], 1);
            perm0[pos] = src0[i];
        }
    } else {
        const int i = (b - nb0) * 256 + tid;
        if (i < E1) {
            const int pos = atomicAdd(&cur1[dst1[i]], 1);
            perm1[pos] = src1[i];
        }
    }
}

// ---- fused aggregate + bf16-MFMA GEMM + epilogue, BOTH passes in one grid --
// Block = 32 dst rows (natural order -> streaming epilogue), 256 threads.
// Phase 1: 8 rows per wave, round-robin; perm index stream pipelined 2-deep
//          (s0=round t, s1=t+1 in regs; prefetch s2=t+2 AFTER issuing the 8
//          row loads, so the accumulate's vmcnt wait leaves the perm loads
//          outstanding). Each round pays one row-load latency, not two.
// Phase 2: wave w computes rows[0:32) x cols[w*64, w*64+64), 16x16x32 MFMA.
__global__ __launch_bounds__(256, 4) void agg_gemm5(
    const float* __restrict__ x_user, const float* __restrict__ x_game,
    const int* __restrict__ perm_rev, const int* __restrict__ off_user,
    const short* __restrict__ Bsw_rev, const float* __restrict__ bb_rev,
    const float* __restrict__ bout_user,
    const int* __restrict__ perm_played, const int* __restrict__ off_game,
    const short* __restrict__ Bsw_played, const float* __restrict__ bb_played,
    const float* __restrict__ bout_game,
    float* __restrict__ outp, int n_user, int n_game, int nb_game) {
    __shared__ short As[32][264];
    __shared__ float bt[32];

    const int tid = threadIdx.x;
    const int wave = __builtin_amdgcn_readfirstlane(tid >> 6);
    const int lane = tid & 63;

    const float* x_src;
    const float* x_res;
    const int* perm;
    const int* off;
    const short* Bsw;
    const float* bb;
    const float* bout;
    float* out;
    int M, r0;
    if ((int)blockIdx.x < nb_game) {
        // game pass first: deeper degrees -> longer blocks scheduled early
        x_src = x_user; x_res = x_game;
        perm = perm_played; off = off_game;
        Bsw = Bsw_played; bb = bb_played; bout = bout_game;
        out = outp + (size_t)n_user * DD;
        M = n_game;
        r0 = (int)blockIdx.x * 32;
    } else {
        x_src = x_game; x_res = x_user;
        perm = perm_rev; off = off_user;
        Bsw = Bsw_rev; bb = bb_rev; bout = bout_user;
        out = outp;
        M = n_user;
        r0 = ((int)blockIdx.x - nb_game) * 32;
    }

    // ---- phase 1: interleaved gather, perm stream pipelined 2 rounds ahead
    int eb[8], deg[8];
    int s0[8], s1[8];
    float4 acc[8];
#pragma unroll
    for (int j = 0; j < 8; ++j) {
        const int r = r0 + wave * 8 + j;
        eb[j] = (r < M) ? off[r] : 0;
        const int e1 = (r < M) ? off[r + 1] : 0;
        deg[j] = e1 - eb[j];
        acc[j].x = 0.f; acc[j].y = 0.f; acc[j].z = 0.f; acc[j].w = 0.f;
        if (lane == 0) bt[wave * 8 + j] = (deg[j] > 0) ? 1.0f : 0.0f;
    }
#pragma unroll
    for (int j = 0; j < 8; ++j) {
        s0[j] = (deg[j] > 0) ? perm[eb[j]] : 0;
        s1[j] = (deg[j] > 1) ? perm[eb[j] + 1] : 0;
    }
    int mdeg = 0;
#pragma unroll
    for (int j = 0; j < 8; ++j) mdeg = max(mdeg, deg[j]);

    for (int t = 0; t < mdeg; ++t) {
        // 1) issue the 8 row loads (oldest in the vmcnt FIFO)
        float4 v[8];
        bool h[8];
#pragma unroll
        for (int j = 0; j < 8; ++j) {
            h[j] = t < deg[j];
            if (h[j])
                v[j] = ((const float4*)(x_src + (size_t)s0[j] * DD))[lane];
        }
        // 2) prefetch perm for round t+2 (stays outstanding during accumulate)
        int s2[8];
#pragma unroll
        for (int j = 0; j < 8; ++j)
            s2[j] = (t + 2 < deg[j]) ? perm[eb[j] + t + 2] : 0;
        // 3) accumulate (waits only on the row loads) + rotate index pipeline
#pragma unroll
        for (int j = 0; j < 8; ++j) {
            if (h[j]) {
                acc[j].x += v[j].x;
                acc[j].y += v[j].y;
                acc[j].z += v[j].z;
                acc[j].w += v[j].w;
            }
            s0[j] = s1[j];
            s1[j] = s2[j];
        }
    }
#pragma unroll
    for (int j = 0; j < 8; ++j) {
        const int lr = wave * 8 + j;
        const float inv = 1.0f / fmaxf((float)deg[j], 1.0f);
        short4 b4;
        b4.x = f2bf(acc[j].x * inv);
        b4.y = f2bf(acc[j].y * inv);
        b4.z = f2bf(acc[j].z * inv);
        b4.w = f2bf(acc[j].w * inv);
        *(short4*)&As[lr][lane * 4] = b4;
    }
    __syncthreads();

    // ---- phase 2: MFMA, 32 rows x 64 cols per wave ----
    const int quad = lane >> 4;
    const int l16 = lane & 15;
    floatx4 cacc[2][4];
#pragma unroll
    for (int rt = 0; rt < 2; ++rt)
#pragma unroll
        for (int ct = 0; ct < 4; ++ct) cacc[rt][ct] = (floatx4){0.f, 0.f, 0.f, 0.f};

    for (int kb8 = 0; kb8 < 8; ++kb8) {
        short8 af[2];
#pragma unroll
        for (int rt = 0; rt < 2; ++rt)
            af[rt] = *(const short8*)&As[rt * 16 + l16][kb8 * 32 + quad * 8];
        short8 bf[4];
        const short* bp = Bsw + (((size_t)(kb8 * 16 + wave * 4) * 64 + lane) << 3);
#pragma unroll
        for (int ct = 0; ct < 4; ++ct)
            bf[ct] = *(const short8*)(bp + (ct << 9));
#pragma unroll
        for (int rt = 0; rt < 2; ++rt)
#pragma unroll
            for (int ct = 0; ct < 4; ++ct)
                cacc[rt][ct] = __builtin_amdgcn_mfma_f32_16x16x32_bf16(
                    af[rt], bf[ct], cacc[rt][ct], 0, 0, 0);
    }

    // ---- epilogue (natural row order -> streaming x_res/out traffic) ----
    float bbv[4], bov[4];
#pragma unroll
    for (int ct = 0; ct < 4; ++ct) {
        const int n = wave * 64 + ct * 16 + l16;
        bbv[ct] = bb[n];
        bov[ct] = bout[n];
    }
#pragma unroll
    for (int rt = 0; rt < 2; ++rt) {
#pragma unroll
        for (int j = 0; j < 4; ++j) {
            const int lr = rt * 16 + quad * 4 + j;
            const int r = r0 + lr;
            if (r < M) {
                const float btv = bt[lr];
                const float* xr = x_res + (size_t)r * DD;
                float* orow = out + (size_t)r * DD;
#pragma unroll
                for (int ct = 0; ct < 4; ++ct) {
                    const int n = wave * 64 + ct * 16 + l16;
                    const float o = cacc[rt][ct][j] + btv * bbv[ct] + bov[ct] + xr[n];
                    orow[n] = fmaxf(o, 0.f);
                }
            }
        }
    }
}

extern "C" void kernel_launch(void* const* d_in, const int* in_sizes, int n_in,
                              void* d_out, int out_size, void* d_ws, size_t ws_size,
                              hipStream_t stream) {
    const float* x_user = (const float*)d_in[0];
    const float* x_game = (const float*)d_in[1];
    const float* Wv_user = (const float*)d_in[6];
    const float* bv_user = (const float*)d_in[7];
    const float* Wout_user = (const float*)d_in[8];
    const float* bout_user = (const float*)d_in[9];
    const float* Wv_game = (const float*)d_in[14];
    const float* bv_game = (const float*)d_in[15];
    const float* Wout_game = (const float*)d_in[16];
    const float* bout_game = (const float*)d_in[17];
    const float* Wm_played = (const float*)d_in[20];
    const float* bm_played = (const float*)d_in[21];
    const float* Wm_rev = (const float*)d_in[24];
    const float* bm_rev = (const float*)d_in[25];
    const int* ei_played_src = (const int*)d_in[26];
    const int* ei_played_dst = (const int*)d_in[27];
    const int* ei_rev_src = (const int*)d_in[28];
    const int* ei_rev_dst = (const int*)d_in[29];

    const int n_user = in_sizes[0] / DD;
    const int n_game = in_sizes[1] / DD;
    const int e_played = in_sizes[26];
    const int e_rev = in_sizes[28];

    float* out = (float*)d_out;
    float* out_user = out;
    float* out_game = out + (size_t)n_user * DD;
    (void)out_game; (void)out_user;

    // ---- workspace layout ----
    float* fws = (float*)d_ws;
    float* T0 = fws;                       // 64K f32
    float* T1 = T0 + DD * DD;              // 64K f32
    float* bb_played = T1 + DD * DD;       // 256
    float* bb_rev = bb_played + DD;        // 256
    short* Bsw_played = (short*)(bb_rev + DD);   // 64K bf16
    short* Bsw_rev = Bsw_played + DD * DD;       // 64K bf16
    int* iws = (int*)(Bsw_rev + DD * DD);
    int* off_game = iws;                      // n_game+1
    int* off_user = off_game + (n_game + 1);  // n_user+1
    int* cursor_game = off_user + (n_user + 1);
    int* cursor_user = cursor_game + n_game;
    int* sums_game = cursor_user + n_user;    // 256
    int* sums_user = sums_game + 256;         // 256
    int* perm_played = sums_user + 256;       // E
    int* perm_rev = perm_played + e_played;   // E
    (void)ws_size; (void)n_in; (void)out_size;

    // ---- zero histograms (off_game & off_user contiguous) ----
    hipMemsetAsync(off_game, 0, (size_t)(n_game + n_user + 2) * sizeof(int), stream);

    const int nbh_p = (e_played + 255) / 256;
    const int nbh_r = (e_rev + 255) / 256;
    const int nch_g = (n_game + SCAN_CHUNK - 1) / SCAN_CHUNK;
    const int nch_u = (n_user + SCAN_CHUNK - 1) / SCAN_CHUNK;

    // A: weight GEMM stage1 + histograms
    fuseA<<<512 + nbh_p + nbh_r, 256, 0, stream>>>(
        Wv_user, Wm_played, T0, Wv_game, Wm_rev, T1,
        ei_played_dst, off_game, e_played, ei_rev_dst, off_user, e_rev);
    // B: weight GEMM stage2 (swizzled bf16) + chunk scans
    fuseB<<<512 + nch_g + nch_u, 256, 0, stream>>>(
        T0, Wout_game, Bsw_played, T1, Wout_user, Bsw_rev,
        off_game, sums_game, n_game, off_user, sums_user, n_user);
    // C: bias fusion + chunk-sum scans
    fuseC<<<4, 256, 0, stream>>>(
        bv_user, Wm_played, bm_played, Wout_game, bb_played,
        bv_game, Wm_rev, bm_rev, Wout_user, bb_rev,
        sums_game, nch_g, sums_user, nch_u);
    // D: scan finalize + cursor init (no memcpys)
    const int ntot = (n_game + 1) + (n_user + 1);
    fuseD<<<(ntot + 255) / 256, 256, 0, stream>>>(
        off_game, sums_game, cursor_game, n_game, e_played,
        off_user, sums_user, cursor_user, n_user, e_rev);
    // E: permute both edge lists
    fuseE<<<nbh_p + nbh_r, 256, 0, stream>>>(
        ei_played_src, ei_played_dst, cursor_game, perm_played, e_played,
        ei_rev_src, ei_rev_dst, cursor_user, perm_rev, e_rev);

    // ---- fused aggregate + GEMM + epilogue, both passes in one grid ----
    const int nb_game = (n_game + 31) / 32;
    const int nb_user = (n_user + 31) / 32;
    agg_gemm5<<<nb_game + nb_user, 256, 0, stream>>>(
        x_user, x_game, perm_rev, off_user, Bsw_rev, bb_rev, bout_user,
        perm_played, off_game, Bsw_played, bb_played, bout_game,
        out, n_user, n_game, nb_game);
}